// Round 1
// baseline (1265.093 us; speedup 1.0000x reference)
//
#include <hip/hip_runtime.h>
#include <stdint.h>
#include <math.h>

// ---- JAX RNG mode: 1 = threefry_partitionable (default since jax 0.4.36),
// ----               0 = legacy split/iota-halves mode
#define RNG_PARTITIONABLE 1

#define NN 128
#define EE 256
#define HH 256

#define OFF_LOGP 0
#define OFF_IDX  32768
#define OFF_INIT 65536
#define OFF_LAST 66048
#define OFF_RS   66560

__device__ __forceinline__ uint32_t rotl32_(uint32_t x, int d){ return (x<<d)|(x>>(32-d)); }

// Threefry-2x32, 20 rounds, JAX key schedule
__device__ __forceinline__ void tf2x32(uint32_t k0, uint32_t k1, uint32_t x0, uint32_t x1,
                                       uint32_t& o0, uint32_t& o1){
  uint32_t k2 = k0 ^ k1 ^ 0x1BD11BDAu;
  x0 += k0; x1 += k1;
#define TF_RND(r) { x0 += x1; x1 = rotl32_(x1,(r)); x1 ^= x0; }
  TF_RND(13) TF_RND(15) TF_RND(26) TF_RND(6)
  x0 += k1; x1 += k2 + 1u;
  TF_RND(17) TF_RND(29) TF_RND(16) TF_RND(24)
  x0 += k2; x1 += k0 + 2u;
  TF_RND(13) TF_RND(15) TF_RND(26) TF_RND(6)
  x0 += k0; x1 += k1 + 3u;
  TF_RND(17) TF_RND(29) TF_RND(16) TF_RND(24)
  x0 += k1; x1 += k2 + 4u;
  TF_RND(13) TF_RND(15) TF_RND(26) TF_RND(6)
  x0 += k2; x1 += k0 + 5u;
#undef TF_RND
  o0 = x0; o1 = x1;
}

// XLA / Eigen f32 tanh rational approximation (matches what XLA emits)
__device__ __forceinline__ float xla_tanhf(float x){
  const float kClamp = 7.90531110763549805f;
  float xc = fminf(fmaxf(x, -kClamp), kClamp);
  float x2 = xc*xc;
  float p = -2.76076847742355e-16f;
  p = fmaf(x2, p, 2.00018790482477e-13f);
  p = fmaf(x2, p, -8.60467152213735e-11f);
  p = fmaf(x2, p, 5.12229709037114e-08f);
  p = fmaf(x2, p, 1.48572235717979e-05f);
  p = fmaf(x2, p, 6.37261928875436e-04f);
  p = fmaf(x2, p, 4.89352455891786e-03f);
  p = xc * p;
  float q = 1.19825839466702e-06f;
  q = fmaf(x2, q, 1.18534705686654e-04f);
  q = fmaf(x2, q, 2.26843463243900e-03f);
  q = fmaf(x2, q, 4.89352518554385e-03f);
  float r = p / q;
  return (fabsf(x) < 0.0004f) ? x : r;
}

// jax.random.gumbel element: uniform(minval=tiny) -> -log(-log(u))
__device__ __forceinline__ float jax_gumbel(uint32_t k0, uint32_t k1, uint32_t t){
  uint32_t o0, o1, bits;
#if RNG_PARTITIONABLE
  tf2x32(k0, k1, 0u, t, o0, o1);
  bits = o0 ^ o1;
#else
  uint32_t p = t & 16383u;                 // half of 32768-element draw
  tf2x32(k0, k1, p, p + 16384u, o0, o1);
  bits = (t < 16384u) ? o0 : o1;
#endif
  float u = __uint_as_float((bits >> 9) | 0x3f800000u) - 1.0f;
  const float kTiny = 1.17549435e-38f;
  u = fmaxf(kTiny, u + kTiny);
  return -logf(-logf(u));
}

// ---------------- small precompute kernels ----------------
__global__ void k_tmp1(const float* __restrict__ liw, const float* __restrict__ Wr,
                       float* __restrict__ tmp1){
  int e = threadIdx.x;
  float acc = 0.f;
  for (int k = 0; k < 2*EE; ++k) acc = fmaf(liw[k], Wr[(size_t)k*EE + e], acc);
  tmp1[e] = acc;
}

__global__ void k_T1(const float* __restrict__ Wr, const float* __restrict__ Wq,
                     float* __restrict__ T1){
  int r = blockIdx.x, h = threadIdx.x;
  float acc = 0.f;
  for (int e = 0; e < EE; ++e) acc = fmaf(Wr[(size_t)r*EE + e], Wq[(size_t)e*HH + h], acc);
  T1[(size_t)r*HH + h] = acc;
}

__global__ void k_c0(const float* __restrict__ tmp1, const float* __restrict__ Wq,
                     float* __restrict__ c0){
  int h = threadIdx.x;
  float acc = 0.f;
  for (int e = 0; e < EE; ++e) acc = fmaf(tmp1[e], Wq[(size_t)e*HH + h], acc);
  c0[h] = acc;
}

__global__ void k_base(const float* __restrict__ lcv, const float* __restrict__ Whbar,
                       const float* __restrict__ bhbar, const float* __restrict__ brest,
                       const float* __restrict__ Wq, const float* __restrict__ bq,
                       float* __restrict__ base){
  __shared__ float sm[EE];
  __shared__ float hb2[EE];
  int b = blockIdx.x, t = threadIdx.x;
  float acc = 0.f;
  const float* p = lcv + (size_t)b*NN*EE + t;
  for (int n = 0; n < NN; ++n) acc += p[(size_t)n*EE];
  sm[t] = acc * 0.0078125f;   // mean over N=128 (exact pow2)
  __syncthreads();
  float a2 = 0.f;
  for (int e = 0; e < EE; ++e) a2 = fmaf(sm[e], Whbar[(size_t)e*EE + t], a2);
  hb2[t] = (a2 + bhbar[t]) + brest[t];
  __syncthreads();
  float a3 = 0.f;
  for (int e = 0; e < EE; ++e) a3 = fmaf(hb2[e], Wq[(size_t)e*HH + t], a3);
  base[(size_t)b*HH + t] = a3 + bq[t];
}

// ---------------- main sequential decoder: 1 block per batch ----------------
__global__ __launch_bounds__(512) void dec_main(
    const float* __restrict__ lcv, const float* __restrict__ onode,
    const int* __restrict__ mask_in, const int* __restrict__ id_in,
    const float* __restrict__ Wk, const float* __restrict__ bk,
    const float* __restrict__ vvec, const float* __restrict__ T1,
    const float* __restrict__ base, const float* __restrict__ c0,
    float* __restrict__ out)
{
  const int b = blockIdx.x;
  const int tid = threadIdx.x;
  const int wid = tid >> 6;
  const int lane = tid & 63;
  const int jl = (wid << 4) + (lane & 15);  // j handled by this thread (4 lanes per j)
  const int grp = lane >> 4;                // h-group 0..3 (h base = 64*grp)

  __shared__ __align__(16) float sB[2*16*272];   // staged Wk / T1b chunks (padded rows)
  __shared__ __align__(16) float q_s[272];       // padded: group stride 68 floats
  __shared__ __align__(16) float v_s[272];
  __shared__ __align__(16) float base_s[EE];
  __shared__ __align__(16) float p1row[EE];
  __shared__ float u_s[NN];
  __shared__ float g_s[NN];
  __shared__ int mask_s[NN];
  __shared__ uint32_t sk0[NN], sk1[NN];
  __shared__ int idx_sh, cur_sh;
#if !RNG_PARTITIONABLE
  __shared__ uint32_t skarr[2*NN];
#endif

  const float NEG_INF = -__builtin_huge_valf();

  // ---- per-block init GEMM: keys[b] and P2[b]=lcv[b]@T1b into registers ----
  float4 kreg[16], p2reg[16];
  #pragma unroll
  for (int c = 0; c < 16; ++c){
    kreg[c]  = make_float4(0.f,0.f,0.f,0.f);
    p2reg[c] = make_float4(0.f,0.f,0.f,0.f);
  }

  const size_t rowA = ((size_t)b*NN + jl)*EE;
  for (int ch = 0; ch < 16; ++ch){
    __syncthreads();
    {
      const int e0 = ch*16;
      for (int s = tid; s < 2048; s += 512){
        const int mat = s >> 10;
        const int r = (s & 1023) >> 6;
        const int c4 = s & 63;
        const int g = c4 >> 4, w = c4 & 15;
        const float* src = mat ? (T1 + (size_t)(EE + e0 + r)*HH)
                               : (Wk + (size_t)(e0 + r)*HH);
        ((float4*)(sB + (size_t)mat*(16*272)))[r*68 + g*17 + w] =
            ((const float4*)src)[c4];
      }
    }
    float areg[16];
    {
      const float4* ap = (const float4*)(lcv + rowA + ch*16);
      #pragma unroll
      for (int qq = 0; qq < 4; ++qq){
        float4 t = ap[qq];
        areg[4*qq+0] = t.x; areg[4*qq+1] = t.y; areg[4*qq+2] = t.z; areg[4*qq+3] = t.w;
      }
    }
    __syncthreads();
    #pragma unroll
    for (int e = 0; e < 16; ++e){
      const float av = areg[e];
      const float4* wrow = (const float4*)(sB + e*272);
      const float4* trow = (const float4*)(sB + 16*272 + e*272);
      #pragma unroll
      for (int c = 0; c < 16; ++c){
        const float4 wv = wrow[grp*17 + c];
        const float4 tv = trow[grp*17 + c];
        kreg[c].x = fmaf(av, wv.x, kreg[c].x);
        kreg[c].y = fmaf(av, wv.y, kreg[c].y);
        kreg[c].z = fmaf(av, wv.z, kreg[c].z);
        kreg[c].w = fmaf(av, wv.w, kreg[c].w);
        p2reg[c].x = fmaf(av, tv.x, p2reg[c].x);
        p2reg[c].y = fmaf(av, tv.y, p2reg[c].y);
        p2reg[c].z = fmaf(av, tv.z, p2reg[c].z);
        p2reg[c].w = fmaf(av, tv.w, p2reg[c].w);
      }
    }
  }
  { // + b_k
    const float4* bk4 = (const float4*)(bk + (grp << 6));
    #pragma unroll
    for (int c = 0; c < 16; ++c){
      float4 t = bk4[c];
      kreg[c].x += t.x; kreg[c].y += t.y; kreg[c].z += t.z; kreg[c].w += t.w;
    }
  }

  // ---- init state ----
  if (tid < 256){
    const int h = tid;
    const float bs = base[(size_t)b*HH + h];
    base_s[h] = bs;
    q_s[(h>>6)*68 + (h&63)] = bs + c0[h];   // query0 = base + (liw@W_rest)@W_q
    v_s[(h>>6)*68 + (h&63)] = vvec[h];
  } else if (tid < 384){
    const int j = tid - 256;
    mask_s[j] = mask_in[(size_t)b*NN + j];
  } else {
#if RNG_PARTITIONABLE
    const int i = tid - 384;
    uint32_t o0,o1; tf2x32(0u, 42u, 0u, (uint32_t)i, o0, o1);
    sk0[i] = o0; sk1[i] = o1;
#else
    const int p = tid - 384;
    uint32_t o0,o1; tf2x32(0u, 42u, (uint32_t)p, (uint32_t)(NN + p), o0, o1);
    skarr[p] = o0; skarr[NN + p] = o1;
#endif
  }
#if !RNG_PARTITIONABLE
  __syncthreads();
  if (tid >= 384){ const int i = tid - 384; sk0[i] = skarr[2*i]; sk1[i] = skarr[2*i+1]; }
#endif
  if (tid == 0){
    cur_sh = 0; idx_sh = 0;
    out[OFF_INIT + 2*b]     = onode[(size_t)b*NN*2 + 0];
    out[OFF_INIT + 2*b + 1] = onode[(size_t)b*NN*2 + 1];
  }
  const int id0 = id_in[0];

  // ---- sequential steps ----
  for (int i = 0; i < NN; ++i){
    __syncthreads();
    // phase U: u[j] = sum_h tanh(keys + q) * v   (+ per-step gumbel table)
    {
      float s = 0.f;
      #pragma unroll
      for (int c = 0; c < 16; ++c){
        const float4 qv = ((const float4*)q_s)[grp*17 + c];
        const float4 vv = ((const float4*)v_s)[grp*17 + c];
        const float4 kv = kreg[c];
        s = fmaf(xla_tanhf(kv.x + qv.x), vv.x, s);
        s = fmaf(xla_tanhf(kv.y + qv.y), vv.y, s);
        s = fmaf(xla_tanhf(kv.z + qv.z), vv.z, s);
        s = fmaf(xla_tanhf(kv.w + qv.w), vv.w, s);
      }
      s += __shfl_xor(s, 16);
      s += __shfl_xor(s, 32);
      if (lane < 16){
        u_s[jl] = s;
        g_s[jl] = jax_gumbel(sk0[i], sk1[i], (uint32_t)(b*NN + jl));
      }
    }
    __syncthreads();
    // phase S: sampling + log_softmax (wave 0)
    if (wid == 0){
      float l0 = 10.0f * xla_tanhf(u_s[lane]);
      float l1 = 10.0f * xla_tanhf(u_s[64 + lane]);
      if (mask_s[lane])    l0 = NEG_INF;
      if (mask_s[64+lane]) l1 = NEG_INF;
      const float y0 = l0 + g_s[lane];
      const float y1 = l1 + g_s[64 + lane];
      float bv; int bi;
      if (y1 > y0){ bv = y1; bi = 64 + lane; } else { bv = y0; bi = lane; }
      #pragma unroll
      for (int off = 1; off < 64; off <<= 1){
        const float ov = __shfl_xor(bv, off);
        const int   oi = __shfl_xor(bi, off);
        if (ov > bv || (ov == bv && oi < bi)){ bv = ov; bi = oi; }
      }
      if (i == 0 && id0 == 0) bi = 0;
      float mm = fmaxf(l0, l1);
      #pragma unroll
      for (int off = 1; off < 64; off <<= 1) mm = fmaxf(mm, __shfl_xor(mm, off));
      float es = expf(l0 - mm) + expf(l1 - mm);
      #pragma unroll
      for (int off = 1; off < 64; off <<= 1) es += __shfl_xor(es, off);
      const float lown = (bi >= 64) ? l1 : l0;
      const float lsel = __shfl(lown, bi & 63);
      const float logp = (lsel - mm) - logf(es);
      if (lane == 0){
        out[OFF_LOGP + b*NN + i] = logp;
        out[OFF_IDX  + b*NN + i] = (float)bi;
        const int cur = cur_sh;
        const float2 pc = ((const float2*)onode)[b*NN + cur];
        const float2 pn = ((const float2*)onode)[b*NN + bi];
        const float dx = pn.x - pc.x, dy = pn.y - pc.y;
        out[OFF_RS + b*NN + i] = sqrtf(dx*dx + dy*dy);
        if (i == NN-1){ out[OFF_LAST + 2*b] = pn.x; out[OFF_LAST + 2*b + 1] = pn.y; }
        cur_sh = bi;
        mask_s[bi] = 1;
        idx_sh = bi;
      }
    }
    __syncthreads();
    // phase P1 (step 0 only): P1row = lcv[b, idx0] @ T1[:E]
    if (i == 0){
      const int i0 = idx_sh;
      if (tid < 256){
        const float* arow = lcv + ((size_t)b*NN + i0)*EE;
        float acc = 0.f;
        for (int e = 0; e < EE; ++e) acc = fmaf(arow[e], T1[(size_t)e*HH + tid], acc);
        p1row[tid] = acc;
      }
      __syncthreads();
    }
    // phase Q: q = base + P1row + P2[idx]  (4 owner lanes write from registers)
    {
      const int idx = idx_sh;
      if (wid == (idx >> 4) && (lane & 15) == (idx & 15)){
        const int hb4 = grp << 4;
        #pragma unroll
        for (int c = 0; c < 16; ++c){
          const float4 b4 = ((const float4*)base_s)[hb4 + c];
          const float4 p4 = ((const float4*)p1row)[hb4 + c];
          const float4 pp = p2reg[c];
          float4 nq;
          nq.x = (b4.x + p4.x) + pp.x;
          nq.y = (b4.y + p4.y) + pp.y;
          nq.z = (b4.z + p4.z) + pp.z;
          nq.w = (b4.w + p4.w) + pp.w;
          ((float4*)q_s)[grp*17 + c] = nq;
        }
      }
    }
  }
}

extern "C" void kernel_launch(void* const* d_in, const int* in_sizes, int n_in,
                              void* d_out, int out_size, void* d_ws, size_t ws_size,
                              hipStream_t stream){
  const float* lcv   = (const float*)d_in[0];
  const float* onode = (const float*)d_in[1];
  const int*   mask  = (const int*)d_in[2];
  const int*   id    = (const int*)d_in[3];
  const float* liw   = (const float*)d_in[4];
  const float* Whbar = (const float*)d_in[5];
  const float* bhbar = (const float*)d_in[6];
  const float* Wrest = (const float*)d_in[7];
  const float* brest = (const float*)d_in[8];
  const float* Wk    = (const float*)d_in[9];
  const float* bk    = (const float*)d_in[10];
  const float* Wq    = (const float*)d_in[11];
  const float* bq    = (const float*)d_in[12];
  const float* vv    = (const float*)d_in[13];

  float* ws   = (float*)d_ws;
  float* T1   = ws;            // 512*256
  float* base = ws + 131072;   // 256*256
  float* tmp1 = ws + 196608;   // 256
  float* c0   = ws + 196864;   // 256
  float* out  = (float*)d_out;

  hipLaunchKernelGGL(k_tmp1, dim3(1),   dim3(256), 0, stream, liw, Wrest, tmp1);
  hipLaunchKernelGGL(k_T1,   dim3(512), dim3(256), 0, stream, Wrest, Wq, T1);
  hipLaunchKernelGGL(k_c0,   dim3(1),   dim3(256), 0, stream, tmp1, Wq, c0);
  hipLaunchKernelGGL(k_base, dim3(256), dim3(256), 0, stream, lcv, Whbar, bhbar, brest, Wq, bq, base);
  hipLaunchKernelGGL(dec_main, dim3(256), dim3(512), 0, stream,
                     lcv, onode, mask, id, Wk, bk, vv, T1, base, c0, out);
}

// Round 2
// 974.967 us; speedup vs baseline: 1.2976x; 1.2976x over previous
//
#include <hip/hip_runtime.h>
#include <stdint.h>
#include <math.h>

#define NN 128
#define EE 256
#define HH 256

#define OFF_LOGP 0
#define OFF_IDX  32768
#define OFF_INIT 65536
#define OFF_LAST 66048
#define OFF_RS   66560

// keys row stride in floats / float4 slots (padded: 260 = 65*4)
#define KST  260
#define KST4 65

__device__ __forceinline__ uint32_t rotl32_(uint32_t x, int d){ return (x<<d)|(x>>(32-d)); }

// Threefry-2x32, 20 rounds, JAX key schedule
__device__ __forceinline__ void tf2x32(uint32_t k0, uint32_t k1, uint32_t x0, uint32_t x1,
                                       uint32_t& o0, uint32_t& o1){
  uint32_t k2 = k0 ^ k1 ^ 0x1BD11BDAu;
  x0 += k0; x1 += k1;
#define TF_RND(r) { x0 += x1; x1 = rotl32_(x1,(r)); x1 ^= x0; }
  TF_RND(13) TF_RND(15) TF_RND(26) TF_RND(6)
  x0 += k1; x1 += k2 + 1u;
  TF_RND(17) TF_RND(29) TF_RND(16) TF_RND(24)
  x0 += k2; x1 += k0 + 2u;
  TF_RND(13) TF_RND(15) TF_RND(26) TF_RND(6)
  x0 += k0; x1 += k1 + 3u;
  TF_RND(17) TF_RND(29) TF_RND(16) TF_RND(24)
  x0 += k1; x1 += k2 + 4u;
  TF_RND(13) TF_RND(15) TF_RND(26) TF_RND(6)
  x0 += k2; x1 += k0 + 5u;
#undef TF_RND
  o0 = x0; o1 = x1;
}

// XLA / Eigen f32 tanh rational approximation (bit-identical to round-1)
__device__ __forceinline__ float xla_tanhf(float x){
  const float kClamp = 7.90531110763549805f;
  float xc = fminf(fmaxf(x, -kClamp), kClamp);
  float x2 = xc*xc;
  float p = -2.76076847742355e-16f;
  p = fmaf(x2, p, 2.00018790482477e-13f);
  p = fmaf(x2, p, -8.60467152213735e-11f);
  p = fmaf(x2, p, 5.12229709037114e-08f);
  p = fmaf(x2, p, 1.48572235717979e-05f);
  p = fmaf(x2, p, 6.37261928875436e-04f);
  p = fmaf(x2, p, 4.89352455891786e-03f);
  p = xc * p;
  float q = 1.19825839466702e-06f;
  q = fmaf(x2, q, 1.18534705686654e-04f);
  q = fmaf(x2, q, 2.26843463243900e-03f);
  q = fmaf(x2, q, 4.89352518554385e-03f);
  float r = p / q;
  return (fabsf(x) < 0.0004f) ? x : r;
}

// jax.random.gumbel element (partitionable threefry) — bit-identical to round-1
__device__ __forceinline__ float jax_gumbel(uint32_t k0, uint32_t k1, uint32_t t){
  uint32_t o0, o1, bits;
  tf2x32(k0, k1, 0u, t, o0, o1);
  bits = o0 ^ o1;
  float u = __uint_as_float((bits >> 9) | 0x3f800000u) - 1.0f;
  const float kTiny = 1.17549435e-38f;
  u = fmaxf(kTiny, u + kTiny);
  return -logf(-logf(u));
}

// ---------------- small precompute kernels (unchanged) ----------------
__global__ void k_tmp1(const float* __restrict__ liw, const float* __restrict__ Wr,
                       float* __restrict__ tmp1){
  int e = threadIdx.x;
  float acc = 0.f;
  for (int k = 0; k < 2*EE; ++k) acc = fmaf(liw[k], Wr[(size_t)k*EE + e], acc);
  tmp1[e] = acc;
}

__global__ void k_T1(const float* __restrict__ Wr, const float* __restrict__ Wq,
                     float* __restrict__ T1){
  int r = blockIdx.x, h = threadIdx.x;
  float acc = 0.f;
  for (int e = 0; e < EE; ++e) acc = fmaf(Wr[(size_t)r*EE + e], Wq[(size_t)e*HH + h], acc);
  T1[(size_t)r*HH + h] = acc;
}

__global__ void k_c0(const float* __restrict__ tmp1, const float* __restrict__ Wq,
                     float* __restrict__ c0){
  int h = threadIdx.x;
  float acc = 0.f;
  for (int e = 0; e < EE; ++e) acc = fmaf(tmp1[e], Wq[(size_t)e*HH + h], acc);
  c0[h] = acc;
}

__global__ void k_base(const float* __restrict__ lcv, const float* __restrict__ Whbar,
                       const float* __restrict__ bhbar, const float* __restrict__ brest,
                       const float* __restrict__ Wq, const float* __restrict__ bq,
                       float* __restrict__ base){
  __shared__ float sm[EE];
  __shared__ float hb2[EE];
  int b = blockIdx.x, t = threadIdx.x;
  float acc = 0.f;
  const float* p = lcv + (size_t)b*NN*EE + t;
  for (int n = 0; n < NN; ++n) acc += p[(size_t)n*EE];
  sm[t] = acc * 0.0078125f;
  __syncthreads();
  float a2 = 0.f;
  for (int e = 0; e < EE; ++e) a2 = fmaf(sm[e], Whbar[(size_t)e*EE + t], a2);
  hb2[t] = (a2 + bhbar[t]) + brest[t];
  __syncthreads();
  float a3 = 0.f;
  for (int e = 0; e < EE; ++e) a3 = fmaf(hb2[e], Wq[(size_t)e*HH + t], a3);
  base[(size_t)b*HH + t] = a3 + bq[t];
}

// ---------------- main sequential decoder: 1 block per batch, 1024 threads ----------------
__global__ __launch_bounds__(1024) void dec_main(
    const float* __restrict__ lcv, const float* __restrict__ onode,
    const int* __restrict__ mask_in, const int* __restrict__ id_in,
    const float* __restrict__ Wk, const float* __restrict__ bk,
    const float* __restrict__ vvec, const float* __restrict__ T1,
    const float* __restrict__ base, const float* __restrict__ c0,
    float* __restrict__ out)
{
  const int b = blockIdx.x;
  const int tid = threadIdx.x;
  const int wid = tid >> 6;
  const int lane = tid & 63;

  __shared__ __align__(16) float keys_lds[NN*KST];   // 133120 B; init staging aliases inside
  __shared__ __align__(16) float q_s[272];           // padded: group stride 68 floats
  __shared__ __align__(16) float v_s[272];
  __shared__ __align__(16) float base_s[HH];
  __shared__ __align__(16) float p1row[HH];
  __shared__ float u_s[NN];
  __shared__ int act_s[NN];
  __shared__ int pos_s[NN];
  __shared__ int mask_s[NN];
  __shared__ uint32_t sk0[NN], sk1[NN];
  __shared__ int idx_sh, cur_sh, L_sh;

  const float NEG_INF = -__builtin_huge_valf();
  const int id0 = id_in[0];

  // ---- init GEMM: keys[b] -> LDS, P2[b]=lcv[b]@T1b -> regs ----
  // wave wid owns j-rows wid*8..wid*8+7; lane owns h = lane*4..+3.
  // e-accumulation order 0..255 sequential fmaf => bit-identical to round-1.
  float4 kacc[8], p2acc[8];
  #pragma unroll
  for (int r = 0; r < 8; ++r){
    kacc[r]  = make_float4(0.f,0.f,0.f,0.f);
    p2acc[r] = make_float4(0.f,0.f,0.f,0.f);
  }
  {
    float* sA = keys_lds;            // [128][36] padded A-chunk
    float* sW = keys_lds + 4608;     // [32][256] Wk chunk
    float* sT = keys_lds + 12800;    // [32][256] T1b chunk
    for (int ch = 0; ch < 8; ++ch){
      const int e0 = ch << 5;
      __syncthreads();
      { // stage lcv chunk: 128 rows x 32e (padded stride 36)
        const int r = tid >> 3, c = tid & 7;
        const float4 t = ((const float4*)(lcv + ((size_t)b*NN + r)*EE + e0))[c];
        ((float4*)sA)[r*9 + c] = t;
      }
      #pragma unroll
      for (int s = 0; s < 2; ++s){ // stage Wk / T1b chunks (32e x 256h each)
        const int idx4 = s*1024 + tid;
        const int e = idx4 >> 6, c = idx4 & 63;
        ((float4*)sW)[idx4] = ((const float4*)(Wk + (size_t)(e0+e)*HH))[c];
        ((float4*)sT)[idx4] = ((const float4*)(T1 + (size_t)(EE+e0+e)*HH))[c];
      }
      __syncthreads();
      const float* aRow = sA + (wid << 3)*36;
      for (int e = 0; e < 32; ++e){
        const float4 wv = ((const float4*)sW)[(e<<6) + lane];  // conflict-free
        const float4 tv = ((const float4*)sT)[(e<<6) + lane];
        #pragma unroll
        for (int r = 0; r < 8; ++r){
          const float av = aRow[r*36 + e];                     // wave-broadcast
          kacc[r].x = fmaf(av, wv.x, kacc[r].x);
          kacc[r].y = fmaf(av, wv.y, kacc[r].y);
          kacc[r].z = fmaf(av, wv.z, kacc[r].z);
          kacc[r].w = fmaf(av, wv.w, kacc[r].w);
          p2acc[r].x = fmaf(av, tv.x, p2acc[r].x);
          p2acc[r].y = fmaf(av, tv.y, p2acc[r].y);
          p2acc[r].z = fmaf(av, tv.z, p2acc[r].z);
          p2acc[r].w = fmaf(av, tv.w, p2acc[r].w);
        }
      }
    }
  }
  __syncthreads();   // staging reads done everywhere -> safe to overwrite region with keys
  {
    const float4 bkv = ((const float4*)bk)[lane];
    // swizzled slot: phys = gh*16 + (c ^ gh), gh = lane>>4, c = lane&15
    const int sphys = ((lane >> 4) << 4) | ((lane & 15) ^ (lane >> 4));
    #pragma unroll
    for (int r = 0; r < 8; ++r){
      const int j = (wid << 3) + r;
      float4 kv = kacc[r];
      kv.x += bkv.x; kv.y += bkv.y; kv.z += bkv.z; kv.w += bkv.w;
      ((float4*)keys_lds)[j*KST4 + sphys] = kv;
    }
  }

  // ---- other shared init ----
  if (tid < HH){
    const float bs = base[(size_t)b*HH + tid];
    base_s[tid] = bs;
    q_s[(tid>>6)*68 + (tid&63)] = bs + c0[tid];   // query0
    v_s[(tid>>6)*68 + (tid&63)] = vvec[tid];
  } else if (tid < HH + NN){
    const int j = tid - HH;
    mask_s[j] = mask_in[(size_t)b*NN + j];
    uint32_t o0,o1; tf2x32(0u, 42u, 0u, (uint32_t)j, o0, o1);
    sk0[j] = o0; sk1[j] = o1;
  } else if (tid == HH + NN){
    out[OFF_INIT + 2*b]     = onode[(size_t)b*NN*2 + 0];
    out[OFF_INIT + 2*b + 1] = onode[(size_t)b*NN*2 + 1];
    cur_sh = 0;
  }
  __syncthreads();
  if (tid == 0){
    int L = 0;
    for (int j = 0; j < NN; ++j){
      if (mask_s[j] == 0){ act_s[L] = j; pos_s[j] = L; ++L; }
    }
    L_sh = L;
  }

  const int grp = tid & 3;       // h-group (h base = grp*64)
  const int aslot = tid >> 2;    // active-list slot handled by this thread

  // ---- sequential steps ----
  for (int i = 0; i < NN; ++i){
    __syncthreads();
    const int L = L_sh;
    // phase U: u[j] for ACTIVE j only (4 lanes per j, 64 sequential h per lane)
    if (aslot < L){
      const int j = act_s[aslot];
      const int kb4 = j*KST4 + (grp << 4);
      const int qb4 = grp*17;
      float s = 0.f;
      #pragma unroll
      for (int c = 0; c < 16; ++c){
        const float4 kv = ((const float4*)keys_lds)[kb4 + (c ^ grp)];
        const float4 qv = ((const float4*)q_s)[qb4 + c];
        const float4 vv = ((const float4*)v_s)[qb4 + c];
        s = fmaf(xla_tanhf(kv.x + qv.x), vv.x, s);
        s = fmaf(xla_tanhf(kv.y + qv.y), vv.y, s);
        s = fmaf(xla_tanhf(kv.z + qv.z), vv.z, s);
        s = fmaf(xla_tanhf(kv.w + qv.w), vv.w, s);
      }
      s += __shfl_xor(s, 1);   // (g0+g1), (g2+g3)
      s += __shfl_xor(s, 2);   // ((g0+g1)+(g2+g3)) — same bracketing as round-1
      if (grp == 0) u_s[j] = s;
    }
    __syncthreads();
    // phase S: logits + gumbel + sample + logp (wave 0)
    if (wid == 0){
      float l0 = 10.0f * xla_tanhf(u_s[lane]);
      float l1 = 10.0f * xla_tanhf(u_s[64 + lane]);
      if (mask_s[lane])      l0 = NEG_INF;
      if (mask_s[64 + lane]) l1 = NEG_INF;
      const float g0 = jax_gumbel(sk0[i], sk1[i], (uint32_t)(b*NN + lane));
      const float g1 = jax_gumbel(sk0[i], sk1[i], (uint32_t)(b*NN + 64 + lane));
      const float y0 = l0 + g0, y1 = l1 + g1;
      float bv; int bi;
      if (y1 > y0){ bv = y1; bi = 64 + lane; } else { bv = y0; bi = lane; }
      float es = __expf(l0) + __expf(l1);   // logits bounded by ±10: no max-shift needed (logp-only)
      #pragma unroll
      for (int off = 1; off < 64; off <<= 1){
        const float ov = __shfl_xor(bv, off);
        const int   oi = __shfl_xor(bi, off);
        es += __shfl_xor(es, off);
        if (ov > bv || (ov == bv && oi < bi)){ bv = ov; bi = oi; }
      }
      if (i == 0 && id0 == 0) bi = 0;
      const float lown = (bi >= 64) ? l1 : l0;
      const float lsel = __shfl(lown, bi & 63);
      const float logp = lsel - __logf(es);
      if (lane == 0){
        out[OFF_LOGP + b*NN + i] = logp;
        out[OFF_IDX  + b*NN + i] = (float)bi;
        const float2 pc = ((const float2*)onode)[b*NN + cur_sh];
        const float2 pn = ((const float2*)onode)[b*NN + bi];
        const float dx = pn.x - pc.x, dy = pn.y - pc.y;
        out[OFF_RS + b*NN + i] = sqrtf(dx*dx + dy*dy);
        if (i == NN-1){ out[OFF_LAST + 2*b] = pn.x; out[OFF_LAST + 2*b + 1] = pn.y; }
        cur_sh = bi;
        idx_sh = bi;
        if (mask_s[bi] == 0){
          mask_s[bi] = 1;
          const int p = pos_s[bi];
          const int Lm = L_sh - 1;
          const int last = act_s[Lm];
          act_s[p] = last;
          pos_s[last] = p;
          L_sh = Lm;
        }
      }
    }
    __syncthreads();
    // phase P1 (step 0 only): p1row = lcv[b, idx0] @ T1[:E]
    if (i == 0){
      if (tid < HH){
        const float* arow = lcv + ((size_t)b*NN + idx_sh)*EE;
        float acc = 0.f;
        for (int e = 0; e < EE; ++e) acc = fmaf(arow[e], T1[(size_t)e*HH + tid], acc);
        p1row[tid] = acc;
      }
      __syncthreads();
    }
    // phase Q: q = base + p1row + P2[idx] (owner wave writes from registers)
    {
      const int idx = idx_sh;
      if (wid == (idx >> 3)){
        const int r2 = idx & 7;
        float4 pp;
        switch (r2){
          case 0: pp = p2acc[0]; break;
          case 1: pp = p2acc[1]; break;
          case 2: pp = p2acc[2]; break;
          case 3: pp = p2acc[3]; break;
          case 4: pp = p2acc[4]; break;
          case 5: pp = p2acc[5]; break;
          case 6: pp = p2acc[6]; break;
          default: pp = p2acc[7]; break;
        }
        const float4 b4 = ((const float4*)base_s)[lane];
        const float4 p4 = ((const float4*)p1row)[lane];
        float4 nq;
        nq.x = (b4.x + p4.x) + pp.x;
        nq.y = (b4.y + p4.y) + pp.y;
        nq.z = (b4.z + p4.z) + pp.z;
        nq.w = (b4.w + p4.w) + pp.w;
        ((float4*)q_s)[((lane >> 4)*17) + (lane & 15)] = nq;
      }
    }
  }
}

extern "C" void kernel_launch(void* const* d_in, const int* in_sizes, int n_in,
                              void* d_out, int out_size, void* d_ws, size_t ws_size,
                              hipStream_t stream){
  const float* lcv   = (const float*)d_in[0];
  const float* onode = (const float*)d_in[1];
  const int*   mask  = (const int*)d_in[2];
  const int*   id    = (const int*)d_in[3];
  const float* liw   = (const float*)d_in[4];
  const float* Whbar = (const float*)d_in[5];
  const float* bhbar = (const float*)d_in[6];
  const float* Wrest = (const float*)d_in[7];
  const float* brest = (const float*)d_in[8];
  const float* Wk    = (const float*)d_in[9];
  const float* bk    = (const float*)d_in[10];
  const float* Wq    = (const float*)d_in[11];
  const float* bq    = (const float*)d_in[12];
  const float* vv    = (const float*)d_in[13];

  float* ws   = (float*)d_ws;
  float* T1   = ws;            // 512*256
  float* base = ws + 131072;   // 256*256
  float* tmp1 = ws + 196608;   // 256
  float* c0   = ws + 196864;   // 256
  float* out  = (float*)d_out;

  hipLaunchKernelGGL(k_tmp1, dim3(1),   dim3(256), 0, stream, liw, Wrest, tmp1);
  hipLaunchKernelGGL(k_T1,   dim3(512), dim3(256), 0, stream, Wrest, Wq, T1);
  hipLaunchKernelGGL(k_c0,   dim3(1),   dim3(256), 0, stream, tmp1, Wq, c0);
  hipLaunchKernelGGL(k_base, dim3(256), dim3(256), 0, stream, lcv, Whbar, bhbar, brest, Wq, bq, base);
  hipLaunchKernelGGL(dec_main, dim3(256), dim3(1024), 0, stream,
                     lcv, onode, mask, id, Wk, bk, vv, T1, base, c0, out);
}

// Round 3
// 800.139 us; speedup vs baseline: 1.5811x; 1.2185x over previous
//
#include <hip/hip_runtime.h>
#include <stdint.h>
#include <math.h>

#define NN 128
#define EE 256
#define HH 256

#define OFF_LOGP 0
#define OFF_IDX  32768
#define OFF_INIT 65536
#define OFF_LAST 66048
#define OFF_RS   66560

// keys row stride in floats / float4 slots (padded: 260 = 65*4)
#define KST  260
#define KST4 65

__device__ __forceinline__ uint32_t rotl32_(uint32_t x, int d){ return (x<<d)|(x>>(32-d)); }

// Threefry-2x32, 20 rounds, JAX key schedule
__device__ __forceinline__ void tf2x32(uint32_t k0, uint32_t k1, uint32_t x0, uint32_t x1,
                                       uint32_t& o0, uint32_t& o1){
  uint32_t k2 = k0 ^ k1 ^ 0x1BD11BDAu;
  x0 += k0; x1 += k1;
#define TF_RND(r) { x0 += x1; x1 = rotl32_(x1,(r)); x1 ^= x0; }
  TF_RND(13) TF_RND(15) TF_RND(26) TF_RND(6)
  x0 += k1; x1 += k2 + 1u;
  TF_RND(17) TF_RND(29) TF_RND(16) TF_RND(24)
  x0 += k2; x1 += k0 + 2u;
  TF_RND(13) TF_RND(15) TF_RND(26) TF_RND(6)
  x0 += k0; x1 += k1 + 3u;
  TF_RND(17) TF_RND(29) TF_RND(16) TF_RND(24)
  x0 += k1; x1 += k2 + 4u;
  TF_RND(13) TF_RND(15) TF_RND(26) TF_RND(6)
  x0 += k2; x1 += k0 + 5u;
#undef TF_RND
  o0 = x0; o1 = x1;
}

// XLA / Eigen f32 tanh rational approx; division via rcp + NR refine + residual
// correction (<=~0.5 ulp vs IEEE; q in [4.89e-3, ~1] so well-conditioned).
// Tiny-|x| select dropped: for |x|<4e-4 the rational differs from x by <5e-11 abs.
__device__ __forceinline__ float xla_tanhf(float x){
  const float kClamp = 7.90531110763549805f;
  float xc = fminf(fmaxf(x, -kClamp), kClamp);
  float x2 = xc*xc;
  float p = -2.76076847742355e-16f;
  p = fmaf(x2, p, 2.00018790482477e-13f);
  p = fmaf(x2, p, -8.60467152213735e-11f);
  p = fmaf(x2, p, 5.12229709037114e-08f);
  p = fmaf(x2, p, 1.48572235717979e-05f);
  p = fmaf(x2, p, 6.37261928875436e-04f);
  p = fmaf(x2, p, 4.89352455891786e-03f);
  p = xc * p;
  float q = 1.19825839466702e-06f;
  q = fmaf(x2, q, 1.18534705686654e-04f);
  q = fmaf(x2, q, 2.26843463243900e-03f);
  q = fmaf(x2, q, 4.89352518554385e-03f);
  float inv = __builtin_amdgcn_rcpf(q);
  inv = fmaf(fmaf(-q, inv, 1.0f), inv, inv);   // Newton refine
  float r = p * inv;
  r = fmaf(fmaf(-q, r, p), inv, r);            // residual correction
  return r;
}

// jax.random.gumbel element (partitionable threefry) — bit-identical to rounds 1/2
__device__ __forceinline__ float jax_gumbel(uint32_t k0, uint32_t k1, uint32_t t){
  uint32_t o0, o1, bits;
  tf2x32(k0, k1, 0u, t, o0, o1);
  bits = o0 ^ o1;
  float u = __uint_as_float((bits >> 9) | 0x3f800000u) - 1.0f;
  const float kTiny = 1.17549435e-38f;
  u = fmaxf(kTiny, u + kTiny);
  return -logf(-logf(u));
}

// ---------------- small precompute kernels (unchanged) ----------------
__global__ void k_tmp1(const float* __restrict__ liw, const float* __restrict__ Wr,
                       float* __restrict__ tmp1){
  int e = threadIdx.x;
  float acc = 0.f;
  for (int k = 0; k < 2*EE; ++k) acc = fmaf(liw[k], Wr[(size_t)k*EE + e], acc);
  tmp1[e] = acc;
}

__global__ void k_T1(const float* __restrict__ Wr, const float* __restrict__ Wq,
                     float* __restrict__ T1){
  int r = blockIdx.x, h = threadIdx.x;
  float acc = 0.f;
  for (int e = 0; e < EE; ++e) acc = fmaf(Wr[(size_t)r*EE + e], Wq[(size_t)e*HH + h], acc);
  T1[(size_t)r*HH + h] = acc;
}

__global__ void k_c0(const float* __restrict__ tmp1, const float* __restrict__ Wq,
                     float* __restrict__ c0){
  int h = threadIdx.x;
  float acc = 0.f;
  for (int e = 0; e < EE; ++e) acc = fmaf(tmp1[e], Wq[(size_t)e*HH + h], acc);
  c0[h] = acc;
}

__global__ void k_base(const float* __restrict__ lcv, const float* __restrict__ Whbar,
                       const float* __restrict__ bhbar, const float* __restrict__ brest,
                       const float* __restrict__ Wq, const float* __restrict__ bq,
                       float* __restrict__ base){
  __shared__ float sm[EE];
  __shared__ float hb2[EE];
  int b = blockIdx.x, t = threadIdx.x;
  float acc = 0.f;
  const float* p = lcv + (size_t)b*NN*EE + t;
  for (int n = 0; n < NN; ++n) acc += p[(size_t)n*EE];
  sm[t] = acc * 0.0078125f;
  __syncthreads();
  float a2 = 0.f;
  for (int e = 0; e < EE; ++e) a2 = fmaf(sm[e], Whbar[(size_t)e*EE + t], a2);
  hb2[t] = (a2 + bhbar[t]) + brest[t];
  __syncthreads();
  float a3 = 0.f;
  for (int e = 0; e < EE; ++e) a3 = fmaf(hb2[e], Wq[(size_t)e*HH + t], a3);
  base[(size_t)b*HH + t] = a3 + bq[t];
}

// ---------------- main sequential decoder: 1 block per batch, 1024 threads ----------------
__global__ __launch_bounds__(1024, 4) void dec_main(
    const float* __restrict__ lcv, const float* __restrict__ onode,
    const int* __restrict__ mask_in, const int* __restrict__ id_in,
    const float* __restrict__ Wk, const float* __restrict__ bk,
    const float* __restrict__ vvec, const float* __restrict__ T1,
    const float* __restrict__ base, const float* __restrict__ c0,
    float* __restrict__ out)
{
  const int b = blockIdx.x;
  const int tid = threadIdx.x;
  const int wid = tid >> 6;
  const int lane = tid & 63;

  __shared__ __align__(16) float keys_lds[NN*KST];   // 133120 B; init staging aliases inside
  __shared__ __align__(16) float q_s[272];           // padded: group stride 68 floats
  __shared__ __align__(16) float v_s[272];
  __shared__ __align__(16) float base_s[HH];
  __shared__ __align__(16) float p1row[HH];
  __shared__ float u_s[NN];
  __shared__ float g2_s[2][NN];                      // double-buffered gumbel rows
  __shared__ int act_s[NN];
  __shared__ int pos_s[NN];
  __shared__ int mask_s[NN];
  __shared__ uint32_t sk0[NN], sk1[NN];
  __shared__ int idx_sh, cur_sh, L_sh;

  const float NEG_INF = -__builtin_huge_valf();
  const int id0 = id_in[0];

  // ---- init GEMM: keys[b] -> LDS, P2[b]=lcv[b]@T1b -> regs ----
  // wave wid owns j-rows wid*8..wid*8+7; lane owns h = lane*4..+3.
  // e-accumulation order 0..255 sequential fmaf => bit-identical to rounds 1/2.
  float4 kacc[8], p2acc[8];
  #pragma unroll
  for (int r = 0; r < 8; ++r){
    kacc[r]  = make_float4(0.f,0.f,0.f,0.f);
    p2acc[r] = make_float4(0.f,0.f,0.f,0.f);
  }
  {
    float* sA = keys_lds;            // [128][36] padded A-chunk
    float* sW = keys_lds + 4608;     // [32][256] Wk chunk
    float* sT = keys_lds + 12800;    // [32][256] T1b chunk
    for (int ch = 0; ch < 8; ++ch){
      const int e0 = ch << 5;
      __syncthreads();
      { // stage lcv chunk: 128 rows x 32e (padded stride 36)
        const int r = tid >> 3, c = tid & 7;
        const float4 t = ((const float4*)(lcv + ((size_t)b*NN + r)*EE + e0))[c];
        ((float4*)sA)[r*9 + c] = t;
      }
      #pragma unroll
      for (int s = 0; s < 2; ++s){ // stage Wk / T1b chunks (32e x 256h each)
        const int idx4 = s*1024 + tid;
        const int e = idx4 >> 6, c = idx4 & 63;
        ((float4*)sW)[idx4] = ((const float4*)(Wk + (size_t)(e0+e)*HH))[c];
        ((float4*)sT)[idx4] = ((const float4*)(T1 + (size_t)(EE+e0+e)*HH))[c];
      }
      __syncthreads();
      const float* aRow = sA + (wid << 3)*36;
      for (int e = 0; e < 32; ++e){
        const float4 wv = ((const float4*)sW)[(e<<6) + lane];  // conflict-free
        const float4 tv = ((const float4*)sT)[(e<<6) + lane];
        #pragma unroll
        for (int r = 0; r < 8; ++r){
          const float av = aRow[r*36 + e];                     // wave-broadcast
          kacc[r].x = fmaf(av, wv.x, kacc[r].x);
          kacc[r].y = fmaf(av, wv.y, kacc[r].y);
          kacc[r].z = fmaf(av, wv.z, kacc[r].z);
          kacc[r].w = fmaf(av, wv.w, kacc[r].w);
          p2acc[r].x = fmaf(av, tv.x, p2acc[r].x);
          p2acc[r].y = fmaf(av, tv.y, p2acc[r].y);
          p2acc[r].z = fmaf(av, tv.z, p2acc[r].z);
          p2acc[r].w = fmaf(av, tv.w, p2acc[r].w);
        }
      }
    }
  }
  __syncthreads();   // staging reads done everywhere -> safe to overwrite region with keys
  {
    const float4 bkv = ((const float4*)bk)[lane];
    // swizzled slot: phys = gh*16 + (c ^ gh), gh = lane>>4, c = lane&15
    const int sphys = ((lane >> 4) << 4) | ((lane & 15) ^ (lane >> 4));
    #pragma unroll
    for (int r = 0; r < 8; ++r){
      const int j = (wid << 3) + r;
      float4 kv = kacc[r];
      kv.x += bkv.x; kv.y += bkv.y; kv.z += bkv.z; kv.w += bkv.w;
      ((float4*)keys_lds)[j*KST4 + sphys] = kv;
    }
  }

  // ---- other shared init ----
  if (tid < HH){
    const float bs = base[(size_t)b*HH + tid];
    base_s[tid] = bs;
    q_s[(tid>>6)*68 + (tid&63)] = bs + c0[tid];   // query0
    v_s[(tid>>6)*68 + (tid&63)] = vvec[tid];
  } else if (tid < HH + NN){
    const int j = tid - HH;
    mask_s[j] = mask_in[(size_t)b*NN + j];
    uint32_t o0,o1; tf2x32(0u, 42u, 0u, (uint32_t)j, o0, o1);
    sk0[j] = o0; sk1[j] = o1;
  } else if (tid == HH + NN){
    out[OFF_INIT + 2*b]     = onode[(size_t)b*NN*2 + 0];
    out[OFF_INIT + 2*b + 1] = onode[(size_t)b*NN*2 + 1];
    cur_sh = 0;
  }
  __syncthreads();
  if (tid == 0){
    int L = 0;
    for (int j = 0; j < NN; ++j){
      if (mask_s[j] == 0){ act_s[L] = j; pos_s[j] = L; ++L; }
    }
    L_sh = L;
  }
  if (wid == 15){  // gumbel row for step 0
    g2_s[0][lane]      = jax_gumbel(sk0[0], sk1[0], (uint32_t)(b*NN + lane));
    g2_s[0][64 + lane] = jax_gumbel(sk0[0], sk1[0], (uint32_t)(b*NN + 64 + lane));
  }

  const int grp = tid & 3;       // h-group (h base = grp*64)
  const int aslot = tid >> 2;    // active-list slot handled by this thread

  // ---- sequential steps ----
  for (int i = 0; i < NN; ++i){
    __syncthreads();
    const int L = L_sh;
    // phase U: u[j] for ACTIVE j only (4 lanes per j, 64 sequential h per lane).
    // tanh values computed into th[16] blocks (ILP), then the accumulator chain
    // runs in the exact original order (bit-identical bracketing).
    if (aslot < L){
      const int j = act_s[aslot];
      const int kb4 = j*KST4 + (grp << 4);
      const int qb4 = grp*17;
      float s = 0.f;
      #pragma unroll
      for (int c4 = 0; c4 < 4; ++c4){
        float th[16];
        #pragma unroll
        for (int cc = 0; cc < 4; ++cc){
          const int c = c4*4 + cc;
          const float4 kv = ((const float4*)keys_lds)[kb4 + (c ^ grp)];
          const float4 qv = ((const float4*)q_s)[qb4 + c];
          th[4*cc+0] = xla_tanhf(kv.x + qv.x);
          th[4*cc+1] = xla_tanhf(kv.y + qv.y);
          th[4*cc+2] = xla_tanhf(kv.z + qv.z);
          th[4*cc+3] = xla_tanhf(kv.w + qv.w);
        }
        #pragma unroll
        for (int cc = 0; cc < 4; ++cc){
          const int c = c4*4 + cc;
          const float4 vv = ((const float4*)v_s)[qb4 + c];
          s = fmaf(th[4*cc+0], vv.x, s);
          s = fmaf(th[4*cc+1], vv.y, s);
          s = fmaf(th[4*cc+2], vv.z, s);
          s = fmaf(th[4*cc+3], vv.w, s);
        }
      }
      s += __shfl_xor(s, 1);   // (g0+g1), (g2+g3)
      s += __shfl_xor(s, 2);   // ((g0+g1)+(g2+g3)) — same bracketing as rounds 1/2
      if (grp == 0) u_s[j] = s;
    } else if (wid == 15 && i + 1 < NN){
      // wave 15 is never active in U (aslot >= 240): precompute next step's gumbels
      const int nb = (i + 1) & 1;
      g2_s[nb][lane]      = jax_gumbel(sk0[i+1], sk1[i+1], (uint32_t)(b*NN + lane));
      g2_s[nb][64 + lane] = jax_gumbel(sk0[i+1], sk1[i+1], (uint32_t)(b*NN + 64 + lane));
    }
    __syncthreads();
    // phase S: logits + gumbel + sample + logp (wave 0)
    if (wid == 0){
      float l0 = 10.0f * xla_tanhf(u_s[lane]);
      float l1 = 10.0f * xla_tanhf(u_s[64 + lane]);
      if (mask_s[lane])      l0 = NEG_INF;
      if (mask_s[64 + lane]) l1 = NEG_INF;
      const float g0 = g2_s[i & 1][lane];
      const float g1 = g2_s[i & 1][64 + lane];
      const float y0 = l0 + g0, y1 = l1 + g1;
      float bv; int bi;
      if (y1 > y0){ bv = y1; bi = 64 + lane; } else { bv = y0; bi = lane; }
      float es = __expf(l0) + __expf(l1);   // logits bounded by ±10 (logp-only path)
      #pragma unroll
      for (int off = 1; off < 64; off <<= 1){
        const float ov = __shfl_xor(bv, off);
        const int   oi = __shfl_xor(bi, off);
        es += __shfl_xor(es, off);
        if (ov > bv || (ov == bv && oi < bi)){ bv = ov; bi = oi; }
      }
      if (i == 0 && id0 == 0) bi = 0;
      const float lown = (bi >= 64) ? l1 : l0;
      const float lsel = __shfl(lown, bi & 63);
      const float logp = lsel - __logf(es);
      if (lane == 0){
        out[OFF_LOGP + b*NN + i] = logp;
        out[OFF_IDX  + b*NN + i] = (float)bi;
        const float2 pc = ((const float2*)onode)[b*NN + cur_sh];
        const float2 pn = ((const float2*)onode)[b*NN + bi];
        const float dx = pn.x - pc.x, dy = pn.y - pc.y;
        out[OFF_RS + b*NN + i] = sqrtf(dx*dx + dy*dy);
        if (i == NN-1){ out[OFF_LAST + 2*b] = pn.x; out[OFF_LAST + 2*b + 1] = pn.y; }
        cur_sh = bi;
        idx_sh = bi;
        if (mask_s[bi] == 0){
          mask_s[bi] = 1;
          const int p = pos_s[bi];
          const int Lm = L_sh - 1;
          const int last = act_s[Lm];
          act_s[p] = last;
          pos_s[last] = p;
          L_sh = Lm;
        }
      }
    }
    __syncthreads();
    // phase P1 (step 0 only): p1row = lcv[b, idx0] @ T1[:E]
    if (i == 0){
      if (tid < HH){
        const float* arow = lcv + ((size_t)b*NN + idx_sh)*EE;
        float acc = 0.f;
        for (int e = 0; e < EE; ++e) acc = fmaf(arow[e], T1[(size_t)e*HH + tid], acc);
        p1row[tid] = acc;
      }
      __syncthreads();
    }
    // phase Q: q = base + p1row + P2[idx] (owner wave writes from registers)
    {
      const int idx = idx_sh;
      if (wid == (idx >> 3)){
        const int r2 = idx & 7;
        float4 pp;
        switch (r2){
          case 0: pp = p2acc[0]; break;
          case 1: pp = p2acc[1]; break;
          case 2: pp = p2acc[2]; break;
          case 3: pp = p2acc[3]; break;
          case 4: pp = p2acc[4]; break;
          case 5: pp = p2acc[5]; break;
          case 6: pp = p2acc[6]; break;
          default: pp = p2acc[7]; break;
        }
        const float4 b4 = ((const float4*)base_s)[lane];
        const float4 p4 = ((const float4*)p1row)[lane];
        float4 nq;
        nq.x = (b4.x + p4.x) + pp.x;
        nq.y = (b4.y + p4.y) + pp.y;
        nq.z = (b4.z + p4.z) + pp.z;
        nq.w = (b4.w + p4.w) + pp.w;
        ((float4*)q_s)[((lane >> 4)*17) + (lane & 15)] = nq;
      }
    }
  }
}

extern "C" void kernel_launch(void* const* d_in, const int* in_sizes, int n_in,
                              void* d_out, int out_size, void* d_ws, size_t ws_size,
                              hipStream_t stream){
  const float* lcv   = (const float*)d_in[0];
  const float* onode = (const float*)d_in[1];
  const int*   mask  = (const int*)d_in[2];
  const int*   id    = (const int*)d_in[3];
  const float* liw   = (const float*)d_in[4];
  const float* Whbar = (const float*)d_in[5];
  const float* bhbar = (const float*)d_in[6];
  const float* Wrest = (const float*)d_in[7];
  const float* brest = (const float*)d_in[8];
  const float* Wk    = (const float*)d_in[9];
  const float* bk    = (const float*)d_in[10];
  const float* Wq    = (const float*)d_in[11];
  const float* bq    = (const float*)d_in[12];
  const float* vv    = (const float*)d_in[13];

  float* ws   = (float*)d_ws;
  float* T1   = ws;            // 512*256
  float* base = ws + 131072;   // 256*256
  float* tmp1 = ws + 196608;   // 256
  float* c0   = ws + 196864;   // 256
  float* out  = (float*)d_out;

  hipLaunchKernelGGL(k_tmp1, dim3(1),   dim3(256), 0, stream, liw, Wrest, tmp1);
  hipLaunchKernelGGL(k_T1,   dim3(512), dim3(256), 0, stream, Wrest, Wq, T1);
  hipLaunchKernelGGL(k_c0,   dim3(1),   dim3(256), 0, stream, tmp1, Wq, c0);
  hipLaunchKernelGGL(k_base, dim3(256), dim3(256), 0, stream, lcv, Whbar, bhbar, brest, Wq, bq, base);
  hipLaunchKernelGGL(dec_main, dim3(256), dim3(1024), 0, stream,
                     lcv, onode, mask, id, Wk, bk, vv, T1, base, c0, out);
}